// Round 1
// baseline (115.311 us; speedup 1.0000x reference)
//
#include <hip/hip_runtime.h>
#include <math.h>

// Problem constants
#define NN 1024      // N
#define DIN 512      // D_IN
#define DD 128       // D

// Workspace layout (floats)
//  xp : 4 * 1024*128  split-K partials of x = inputs@weight
//  zp : 8 * 1024*128  split-K partials of z = adj@x
//  x  : 1024*128
//  z  : 1024*128
//  u  : 256           u = W2 @ w3[:128]
//  a  : 1024          a_i = relu(z_i) . u[:128]
//  b  : 1024          b_j = relu(z_j) . u[128:]
static constexpr long XP_OFF = 0;
static constexpr long ZP_OFF = XP_OFF + 4L * NN * DD;       //  524288
static constexpr long X_OFF  = ZP_OFF + 8L * NN * DD;       // 1572864
static constexpr long Z_OFF  = X_OFF + (long)NN * DD;       // 1703936
static constexpr long U_OFF  = Z_OFF + (long)NN * DD;       // 1835008
static constexpr long A_OFF  = U_OFF + 256;
static constexpr long B_OFF  = A_OFF + NN;
// total = B_OFF + NN = 1837312 floats ~= 7.3 MB

// ---------------------------------------------------------------------------
// Split-K fp32 GEMM partial: Cp[s] (M x 128) += A[M x K_chunk_s] @ B[K_chunk_s x 128]
// grid.x = M/32 row-blocks, grid.y = K/Kc splits; block = 256 threads.
// Thread (tx=t&31, ty=t>>5) computes rows {ty+8*mr} x cols {tx+32*mc}, 4x4.
__global__ __launch_bounds__(256) void gemm_part(
    const float* __restrict__ A, const float* __restrict__ B,
    float* __restrict__ Cp, int K, int Kc) {
  const int t = threadIdx.x;
  const int tx = t & 31;
  const int ty = t >> 5;
  const int row0 = blockIdx.x * 32;
  const int k0 = blockIdx.y * Kc;

  float acc[4][4] = {};

  for (int k = k0; k < k0 + Kc; k += 4) {
    // B block: 4 k-rows x 4 col-groups (scalar, wave-coalesced 128B + broadcast)
    float bv[4][4];
#pragma unroll
    for (int kk = 0; kk < 4; ++kk) {
      const float* Brow = &B[(long)(k + kk) * DD + tx];
#pragma unroll
      for (int mc = 0; mc < 4; ++mc) bv[kk][mc] = Brow[32 * mc];
    }
#pragma unroll
    for (int mr = 0; mr < 4; ++mr) {
      const int r = row0 + ty + 8 * mr;
      const float4 av = *(const float4*)&A[(long)r * K + k];
      const float ar[4] = {av.x, av.y, av.z, av.w};
#pragma unroll
      for (int kk = 0; kk < 4; ++kk)
#pragma unroll
        for (int mc = 0; mc < 4; ++mc) acc[mr][mc] += ar[kk] * bv[kk][mc];
    }
  }

  float* Cs = Cp + (long)blockIdx.y * NN * DD;
#pragma unroll
  for (int mr = 0; mr < 4; ++mr) {
    const int r = row0 + ty + 8 * mr;
#pragma unroll
    for (int mc = 0; mc < 4; ++mc) {
      Cs[(long)r * DD + tx + 32 * mc] = acc[mr][mc];
    }
  }
}

// ---------------------------------------------------------------------------
// Reduce 4 x-partials -> x ; block 0 additionally computes u = W2 @ w3[:128].
__global__ __launch_bounds__(256) void reduce_x_u(
    const float* __restrict__ xp, float* __restrict__ x,
    const float* __restrict__ W2, const float* __restrict__ w3,
    float* __restrict__ u) {
  const long i = (long)blockIdx.x * 256 + threadIdx.x;  // 0 .. 131071
  const long S = (long)NN * DD;
  x[i] = xp[i] + xp[S + i] + xp[2 * S + i] + xp[3 * S + i];

  if (blockIdx.x == 0) {
    const int kq = threadIdx.x;  // 0..255
    float uu = 0.f;
#pragma unroll 4
    for (int l = 0; l < DD; ++l) uu += W2[(long)kq * DD + l] * w3[l];
    u[kq] = uu;
  }
}

// ---------------------------------------------------------------------------
// Reduce 8 z-partials -> z ; compute a_i, b_i per row. grid = 1024, block = 64.
__global__ __launch_bounds__(64) void finalize_z(
    const float* __restrict__ zp, float* __restrict__ z,
    const float* __restrict__ u, const float* __restrict__ w3,
    float* __restrict__ a, float* __restrict__ b) {
  const int i = blockIdx.x;
  const int t = threadIdx.x;  // 0..63
  const long S = (long)NN * DD;
  float acc_a = 0.f, acc_b = 0.f;
#pragma unroll
  for (int m = 0; m < 2; ++m) {
    const int k = t + 64 * m;
    float s = 0.f;
#pragma unroll
    for (int p = 0; p < 8; ++p) s += zp[p * S + (long)i * DD + k];
    z[(long)i * DD + k] = s;
    const float rz = s > 0.f ? s : 0.f;
    acc_a += rz * u[k];
    acc_b += rz * u[DD + k];
  }
#pragma unroll
  for (int off = 32; off > 0; off >>= 1) {
    acc_a += __shfl_down(acc_a, off);
    acc_b += __shfl_down(acc_b, off);
  }
  if (t == 0) {
    a[i] = acc_a;
    b[i] = acc_b;
  }
}

// ---------------------------------------------------------------------------
// Decode tile: out[i,j] = sigmoid(a[i] + b[j] + sum_k z[i,k]*z[j,k]*w3[128+k])
// 64x64 tile per block, 256 threads, 4x4 per thread.
// LDS: [64][128] fp32 per operand, XOR-swizzled (k4 ^ ((row&7)<<2)) so that
// strided column reads (c = tx+16m) hit all 32 banks at 2-way (free).
__global__ __launch_bounds__(256) void decode_tile(
    const float* __restrict__ z, const float* __restrict__ w3,
    const float* __restrict__ a, const float* __restrict__ b,
    float* __restrict__ out) {
  __shared__ float zl[64 * DD];   // rows i0..i0+63 of z
  __shared__ float zwl[64 * DD];  // rows j0..j0+63 of z * w3b
  const int t = threadIdx.x;
  const int i0 = blockIdx.y * 64;
  const int j0 = blockIdx.x * 64;

  // Stage: each thread 8 float4 per operand; coalesced global, swizzled LDS.
#pragma unroll
  for (int s = 0; s < 8; ++s) {
    const int q = s * 256 + t;          // 0..2047
    const int r = q >> 5;               // 0..63
    const int k4 = (q & 31) << 2;       // 0..124
    const int sw = r * DD + (k4 ^ ((r & 7) << 2));
    const float4 v = *(const float4*)&z[(long)(i0 + r) * DD + k4];
    *(float4*)&zl[sw] = v;
    float4 w = *(const float4*)&z[(long)(j0 + r) * DD + k4];
    const float4 c = *(const float4*)&w3[DD + k4];
    w.x *= c.x; w.y *= c.y; w.z *= c.z; w.w *= c.w;
    *(float4*)&zwl[sw] = w;
  }
  __syncthreads();

  const int tx = t & 15;
  const int ty = t >> 4;
  float acc[4][4] = {};

  for (int k4 = 0; k4 < DD; k4 += 4) {
    float4 ar[4], bc[4];
#pragma unroll
    for (int m = 0; m < 4; ++m) {
      const int R = ty + 16 * m;
      ar[m] = *(const float4*)&zl[R * DD + (k4 ^ ((R & 7) << 2))];
    }
#pragma unroll
    for (int m = 0; m < 4; ++m) {
      const int C = tx + 16 * m;
      bc[m] = *(const float4*)&zwl[C * DD + (k4 ^ ((C & 7) << 2))];
    }
#pragma unroll
    for (int mr = 0; mr < 4; ++mr)
#pragma unroll
      for (int mc = 0; mc < 4; ++mc)
        acc[mr][mc] += ar[mr].x * bc[mc].x + ar[mr].y * bc[mc].y +
                       ar[mr].z * bc[mc].z + ar[mr].w * bc[mc].w;
  }

#pragma unroll
  for (int mr = 0; mr < 4; ++mr) {
    const int i = i0 + ty + 16 * mr;
    const float ai = a[i];
#pragma unroll
    for (int mc = 0; mc < 4; ++mc) {
      const int j = j0 + tx + 16 * mc;
      const float s = ai + b[j] + acc[mr][mc];
      out[(long)i * NN + j] = 1.0f / (1.0f + __expf(-s));
    }
  }
}

// ---------------------------------------------------------------------------
extern "C" void kernel_launch(void* const* d_in, const int* in_sizes, int n_in,
                              void* d_out, int out_size, void* d_ws, size_t ws_size,
                              hipStream_t stream) {
  (void)in_sizes; (void)n_in; (void)out_size; (void)ws_size;
  const float* inputs = (const float*)d_in[0];   // (1024, 512)
  const float* adj    = (const float*)d_in[1];   // (1024, 1024)
  const float* weight = (const float*)d_in[2];   // (512, 128)
  const float* W2     = (const float*)d_in[3];   // (256, 128)
  const float* w3     = (const float*)d_in[4];   // (256,)
  // d_in[5], d_in[6] (train edges) are unused by the reference output.
  float* out = (float*)d_out;

  float* ws = (float*)d_ws;
  float* xp = ws + XP_OFF;
  float* zp = ws + ZP_OFF;
  float* x  = ws + X_OFF;
  float* z  = ws + Z_OFF;
  float* u  = ws + U_OFF;
  float* a  = ws + A_OFF;
  float* b  = ws + B_OFF;

  // 1) x partials: inputs (1024x512) @ weight (512x128), split-K 4
  gemm_part<<<dim3(32, 4), 256, 0, stream>>>(inputs, weight, xp, DIN, DIN / 4);
  // 2) reduce x, compute u
  reduce_x_u<<<512, 256, 0, stream>>>(xp, x, W2, w3, u);
  // 3) z partials: adj (1024x1024) @ x (1024x128), split-K 8
  gemm_part<<<dim3(32, 8), 256, 0, stream>>>(adj, x, zp, NN, NN / 8);
  // 4) finalize z, a, b
  finalize_z<<<1024, 64, 0, stream>>>(zp, z, u, w3, a, b);
  // 5) decode: out = sigmoid(a_i + b_j + z_i . (z_j * w3b))
  decode_tile<<<dim3(16, 16), 256, 0, stream>>>(z, w3, a, b, out);
}